// Round 11
// baseline (107.023 us; speedup 1.0000x reference)
//
#include <hip/hip_runtime.h>
#include <math.h>

// BIMM2D: M=250000 points, P=4 interior phases, K=6 interface pairs, N_MC=64
#define KN 384            // K * N_MC table entries
#define TPB 256

// Device-global scratch. g_ctr is module-init 0 and self-restored by the last
// block each launch -> graph-replay safe, independent of d_ws poison.
__device__ double g_part[1024];
__device__ int    g_ctr = 0;

__device__ __forceinline__ float fexp2(float x) {
  return __builtin_amdgcn_exp2f(x);   // native v_exp_f32
}

// R11 = R7 + explicit software pipeline.
// R7 measured: 41.9us, VALUBusy 61%, VGPR 24 -> compiler had no headroom to
// hoist ds_reads; every 4-entry group stalled on ~120cy LDS latency with only
// ~3.8 waves/SIMD to cover it. R11 prefetches the NEXT 8-entry group's six
// float4s into named registers while computing the current group (2-stage
// pipeline), and uses 8 independent accumulators for trans-latency ILP.
// Per entry: sub, mul, 2 fma (a1,a2), 2 exp2, 2 accum-fma = 6 VALU + 2 trans.
__global__ __launch_bounds__(TPB, 4) void fused_kernel(
    const float* __restrict__ u, const float* __restrict__ v,
    const float* __restrict__ eps, const float* __restrict__ I,
    const float* __restrict__ W, const float* __restrict__ sb_,
    const float* __restrict__ sn_, const float* __restrict__ d_,
    const float* __restrict__ r_, float* __restrict__ out,
    int M, int nb) {
  __shared__ float stx[KN], sty[KN], stz[KN];
  __shared__ double red[TPB];
  __shared__ int    slast;
  const int tid = threadIdx.x;
  const int i   = blockIdx.x * TPB + tid;

  // hoist point load to overlap with the prelude
  float uu = 0.f, vv = 1.f;
  if (i < M) { uu = u[i]; vv = v[i]; }

  // ---- folded constants (uniform; float, faithful to f32 reference) ----
  const float sb  = sb_[0];
  const float sn  = sn_[0];
  const float dd  = d_[0];
  const float rho = tanhf(r_[0]);
  const float s2  = sn * sn * (1.f - rho);      // sr^2
  const float sr  = sqrtf(s2);
  const float isn = 1.f / sn;
  const float inv_s2 = 1.f / s2;
  const float LOG2E = 1.4426950408889634f;
  const float SQH   = sqrtf(0.5f * LOG2E);      // sqrt(0.5*log2 e)

  float wmax = W[0];
  for (int j = 1; j < 10; ++j) wmax = fmaxf(wmax, W[j]);
  float se = 0.f;
  for (int j = 0; j < 10; ++j) se += expf(W[j] - wmax);
  const float lse = wmax + logf(se);

  const float LOG2PI_ = 1.8378770664093453f;
  const float LOG2_   = 0.6931471805599453f;
  const float LGG32   = -0.12078223763524522f;  // log(gamma(1.5))
  const float LOGPI_  = 1.1447298858494002f;
  const float Cterm = -logf(sn) - 0.5f * LOG2PI_ - logf(sr) - 0.5f * LOGPI_;
  const float Cint0 = LOG2_ - LGG32 - 3.f * logf(sr) - logf(sn) - 0.5f * LOG2PI_;

  float wint[4], cq[4];
#pragma unroll
  for (int p = 0; p < 4; ++p) {
    wint[p] = expf(W[p] - lse + Cint0);
    cq[p]   = I[p] * isn * SQH;
  }

  // ---- per-(k,n) table into LDS (SoA, exp2-folded) ----
  // stx = In/sn*SQH, sty = (2G/s2)*log2e, stz = wk*exp(-G^2/s2)/G
  const int IAc[6] = {0, 0, 0, 1, 1, 2};
  const int IBc[6] = {1, 2, 3, 2, 3, 3};
  for (int t = tid; t < KN; t += TPB) {
    const int k = t >> 6;
    const float Ia = I[IAc[k]], Ib = I[IBc[k]];
    const float wk = expf(W[4 + k] - lse + Cterm) * (1.0f / 64.0f);
    const float e  = eps[t];
    const float x  = e * 2.f * dd * sb - dd * sb;
    const float y  = x / (1.4142135623730951f * sb);
    const float In = (erff(y) + 1.f) * 0.5f * (Ib - Ia) + Ia;
    const float qq = 2.f * (In - Ia) / (Ib - Ia) - 1.f;
    const float gi = erfinvf(qq);
    const float G  = (Ib - Ia) * 0.3989422804014327f / sb * expf(-gi * gi);
    stx[t] = In * isn * SQH;
    sty[t] = 2.f * inv_s2 * G * LOG2E;
    stz[t] = wk * expf(-G * G * inv_s2) / G;
  }

  // ---- per-thread point prelude ----
  // acc(point) = c1 + c0 * S,  S = sum over entries of tz*(e1-e2)
  // c0 = v*g, c1 = v^2*g*aint, g = exp(-v^2/s2); pad threads: c0=0, c1=1.
  const float us = uu * isn * SQH;
  const float gg = fexp2(-vv * vv * inv_s2 * LOG2E);
  float aint = 0.f;
#pragma unroll
  for (int p = 0; p < 4; ++p) {
    const float dq = us - cq[p];
    aint = fmaf(wint[p], fexp2(-dq * dq), aint);
  }
  const float c0 = (i < M) ? vv * gg : 0.f;
  const float c1 = (i < M) ? vv * vv * gg * aint : 1.f;

  __syncthreads();

  // ---- main loop: 48 groups of 8 entries, 2-stage software pipeline ----
#define ENT(TX, TY, TZ, S)                         \
  {                                                \
    const float du = us - (TX);                    \
    const float nd = du * -du;                     \
    const float a1 = fmaf(vv, (TY), nd);           \
    const float a2 = fmaf(vv, -(TY), nd);          \
    S = fmaf((TZ), fexp2(a1), S);                  \
    S = fmaf(-(TZ), fexp2(a2), S);                 \
  }

  float S0 = 0.f, S1 = 0.f, S2 = 0.f, S3 = 0.f;
  float S4 = 0.f, S5 = 0.f, S6 = 0.f, S7 = 0.f;
  const float4* px = (const float4*)stx;   // 96 float4s
  const float4* py = (const float4*)sty;
  const float4* pz = (const float4*)stz;
  float4 Xa = px[0], Ya = py[0], Za = pz[0];
  float4 Xb = px[1], Yb = py[1], Zb = pz[1];
#pragma unroll 2
  for (int g = 1; g <= 48; ++g) {
    // prefetch next group's six float4s (last iter redundantly re-reads 47)
    const int gn = (g < 48) ? g : 47;
    const float4 Xa2 = px[2 * gn + 0], Ya2 = py[2 * gn + 0], Za2 = pz[2 * gn + 0];
    const float4 Xb2 = px[2 * gn + 1], Yb2 = py[2 * gn + 1], Zb2 = pz[2 * gn + 1];
    // compute current group from registers (no LDS dependency)
    ENT(Xa.x, Ya.x, Za.x, S0) ENT(Xa.y, Ya.y, Za.y, S1)
    ENT(Xa.z, Ya.z, Za.z, S2) ENT(Xa.w, Ya.w, Za.w, S3)
    ENT(Xb.x, Yb.x, Zb.x, S4) ENT(Xb.y, Yb.y, Zb.y, S5)
    ENT(Xb.z, Yb.z, Zb.z, S6) ENT(Xb.w, Yb.w, Zb.w, S7)
    Xa = Xa2; Ya = Ya2; Za = Za2;
    Xb = Xb2; Yb = Yb2; Zb = Zb2;
  }
#undef ENT
  const float S = ((S0 + S1) + (S2 + S3)) + ((S4 + S5) + (S6 + S7));

  // per-point log-likelihood (pad threads: log(1) = 0)
  double mysum = (double)__logf(fmaf(c0, S, c1));

  // ---- block reduction (deterministic tree) ----
  red[tid] = mysum;
  __syncthreads();
  for (int s = TPB / 2; s > 0; s >>= 1) {
    if (tid < s) red[tid] += red[tid + s];
    __syncthreads();
  }
  if (tid == 0)
    __hip_atomic_store(&g_part[blockIdx.x], red[0], __ATOMIC_RELAXED,
                       __HIP_MEMORY_SCOPE_AGENT);

  // ---- last-block-done final reduction (fixed order -> deterministic) ----
  if (tid == 0) {
    const int c = __hip_atomic_fetch_add(&g_ctr, 1, __ATOMIC_ACQ_REL,
                                         __HIP_MEMORY_SCOPE_AGENT);
    slast = (c == nb - 1) ? 1 : 0;
  }
  __syncthreads();
  if (slast) {
    double s = 0.0;
    for (int j = tid; j < nb; j += TPB)
      s += __hip_atomic_load(&g_part[j], __ATOMIC_RELAXED,
                             __HIP_MEMORY_SCOPE_AGENT);
    red[tid] = s;
    __syncthreads();
    for (int k2 = TPB / 2; k2 > 0; k2 >>= 1) {
      if (tid < k2) red[tid] += red[tid + k2];
      __syncthreads();
    }
    if (tid == 0) {
      out[0] = (float)(-red[0] / (double)M);
      __hip_atomic_store(&g_ctr, 0, __ATOMIC_RELAXED,
                         __HIP_MEMORY_SCOPE_AGENT);  // restore for next replay
    }
  }
}

extern "C" void kernel_launch(void* const* d_in, const int* in_sizes, int n_in,
                              void* d_out, int out_size, void* d_ws, size_t ws_size,
                              hipStream_t stream) {
  const float* u   = (const float*)d_in[0];
  const float* v   = (const float*)d_in[1];
  const float* eps = (const float*)d_in[2];
  const float* I   = (const float*)d_in[3];
  const float* W   = (const float*)d_in[4];
  const float* sb  = (const float*)d_in[5];
  const float* sn  = (const float*)d_in[6];
  const float* dd  = (const float*)d_in[7];
  const float* r   = (const float*)d_in[8];
  const int M  = in_sizes[0];
  const int nb = (M + TPB - 1) / TPB;   // 977 for M=250000 (g_part holds 1024)
  hipLaunchKernelGGL(fused_kernel, dim3(nb), dim3(TPB), 0, stream,
                     u, v, eps, I, W, sb, sn, dd, r, (float*)d_out, M, nb);
}